// Round 3
// baseline (174.820 us; speedup 1.0000x reference)
//
#include <hip/hip_runtime.h>
#include <hip/hip_bf16.h>

// Problem constants (reference: B=2048, F=512, U=512, G=64, REG_STRENGTH=1.0)
#define B_SZ 2048
#define F_SZ 512
#define U_SZ 512
#define G_SZ 64
#define REG_STRENGTH 1.0f

// MFMA grouped-GEMM tiling: block = 256 threads (4 waves), tile BM x BN,
// waves split M (16 rows each). BM=64 => exactly ceil(cnt/64)=1 chunk per
// group in the typical case => W read from HBM exactly once.
#define BM 64
#define BN 64
#define BK 64
#define NTILES (U_SZ / BN)             // 8
#define MAXCHUNKS (B_SZ / BM + G_SZ)   // 96 (worst-case chunk count)
#define XSTR 72   // LDS row stride in bf16 elems (64 + 8 pad; 144 B, 16B-mult)
#define WSTR 72

typedef __attribute__((ext_vector_type(8))) short bf16x8;  // 8 bf16 = 4 VGPR
typedef __attribute__((ext_vector_type(4))) float f32x4;

// Workspace int layout
#define WS_WSF      0   // float accumulator: weighted (w+b) reg loss
#define WS_TICKET   1
#define WS_NCH      2
#define WS_COUNTS   4
#define WS_ROWSTART (4 + G_SZ)
#define WS_ORDER    (4 + 2 * G_SZ)
#define WS_CHUNKS   (4 + 2 * G_SZ + B_SZ)
// total ints = 4 + 128 + 2048 + 96 = 2276 (~9.1 KB)

__device__ __forceinline__ unsigned short f2bf(float f) {
  unsigned u = __float_as_uint(f);
  u += 0x7FFFu + ((u >> 16) & 1u);  // round-to-nearest-even
  return (unsigned short)(u >> 16);
}

// ---------------------------------------------------------------------------
// Kernel A: histogram gid -> counts, prefix -> rowstart, scatter -> order,
// build chunk worklist (g, r0) with BM-row granularity. Zero wsf/ticket.
// ---------------------------------------------------------------------------
__global__ __launch_bounds__(1024) void prep_kernel(
    const int* __restrict__ gid, int* __restrict__ wsi) {
  __shared__ int cnt_s[G_SZ];
  __shared__ int cur_s[G_SZ];
  __shared__ int chk_s[G_SZ];
  const int tid = threadIdx.x;

  if (tid < G_SZ) cnt_s[tid] = 0;
  if (tid == 0) { ((float*)wsi)[WS_WSF] = 0.0f; wsi[WS_TICKET] = 0; }
  __syncthreads();

  for (int b = tid; b < B_SZ; b += 1024) atomicAdd(&cnt_s[gid[b]], 1);
  __syncthreads();

  if (tid == 0) {
    int run = 0, crun = 0;
    for (int g = 0; g < G_SZ; ++g) {
      cur_s[g] = run;
      chk_s[g] = crun;
      run += cnt_s[g];
      crun += (cnt_s[g] + BM - 1) / BM;
    }
    wsi[WS_NCH] = crun;
  }
  __syncthreads();

  if (tid < G_SZ) {
    wsi[WS_COUNTS + tid] = cnt_s[tid];
    wsi[WS_ROWSTART + tid] = cur_s[tid];
    const int nch = (cnt_s[tid] + BM - 1) / BM;
    const int cs = chk_s[tid];
    for (int i = 0; i < nch; ++i)
      wsi[WS_CHUNKS + cs + i] = tid | ((i * BM) << 8);  // g | (r0<<8)
  }
  __syncthreads();  // rowstart snapshot taken before scatter mutates cur_s

  for (int b = tid; b < B_SZ; b += 1024) {
    int pos = atomicAdd(&cur_s[gid[b]], 1);
    wsi[WS_ORDER + pos] = b;
  }
}

// ---------------------------------------------------------------------------
// Kernel B: bf16-MFMA grouped GEMM. block = (u-tile x, chunk slot y).
// Each block: 64 rows (padded) x 64 cols, K=512. 4 waves split M.
// Fuses sum((W-W0)^2) on the r0==0 chunk (f32 values, pre-conversion) and
// the b-loss on (x==0, r0==0); last block (ticket) writes the scalar.
// ---------------------------------------------------------------------------
__global__ __launch_bounds__(256) void gemm_kernel(
    const float* __restrict__ x, const float* __restrict__ w_mu,
    const float* __restrict__ b_mu, const float* __restrict__ w0_mu,
    const float* __restrict__ b0_mu, float* __restrict__ out,
    int* __restrict__ wsi) {
  const int tid = threadIdx.x;
  const int lane = tid & 63;
  const int wave = tid >> 6;
  const int nch = wsi[WS_NCH];
  const int slot = blockIdx.y;

  __shared__ __align__(16) unsigned short Xbf[BM][XSTR];
  __shared__ __align__(16) unsigned short Wbf[BN][WSTR];
  __shared__ float redw[4];

  if (slot < nch) {
    const int entry = wsi[WS_CHUNKS + slot];
    const int g = entry & 0xFF;
    const int r0 = entry >> 8;
    const int cnt = wsi[WS_COUNTS + g];
    const int rs = wsi[WS_ROWSTART + g];
    const int n0 = blockIdx.x * BN;
    const bool do_reg = (r0 == 0);
    const float* __restrict__ Wg = w_mu + (size_t)g * (U_SZ * F_SZ);
    float regp = 0.0f;

    // fused bias reg loss: one block per group
    if (do_reg && blockIdx.x == 0) {
      for (int i = tid; i < U_SZ; i += 256) {
        float d = b_mu[(g << 9) + i] - b0_mu[i];
        regp += d * d;
      }
    }

    // staging mapping: idx = tid + 256*j -> row = sr + 16*j, f4-col = skq
    const int sr = tid >> 4;    // 0..15
    const int skq = tid & 15;   // 0..15 (16 float4 per 64-float row)
    const float* xptr[4];
    const float* wptr[4];
#pragma unroll
    for (int j = 0; j < 4; ++j) {
      int r = r0 + sr + 16 * j;
      if (r >= cnt) r = cnt - 1;  // clamp; those rows are never stored
      xptr[j] = x + (size_t)wsi[WS_ORDER + rs + r] * F_SZ + skq * 4;
      wptr[j] = Wg + (size_t)(n0 + sr + 16 * j) * F_SZ + skq * 4;
    }

    // MFMA fragment addressing
    const int fl = lane & 15;   // A row / B col / D col
    const int fq = lane >> 4;   // quad
    const unsigned short* aF = &Xbf[wave * 16 + fl][fq * 8];
    const unsigned short* bF = &Wbf[fl][fq * 8];

    f32x4 acc[4] = {{0.f, 0.f, 0.f, 0.f}, {0.f, 0.f, 0.f, 0.f},
                    {0.f, 0.f, 0.f, 0.f}, {0.f, 0.f, 0.f, 0.f}};

    float4 xp[4], wp[4], w0p[4];
#pragma unroll
    for (int j = 0; j < 4; ++j) {
      xp[j] = *(const float4*)(xptr[j]);
      wp[j] = *(const float4*)(wptr[j]);
    }
    if (do_reg)
#pragma unroll
      for (int j = 0; j < 4; ++j)
        w0p[j] = *(const float4*)(w0_mu + (size_t)(n0 + sr + 16 * j) * F_SZ + skq * 4);

    for (int kc = 0; kc < F_SZ; kc += BK) {
      __syncthreads();  // previous chunk's LDS readers done
      // ---- stage prefetched f32 -> bf16 LDS (+ fused W reg loss) ----
#pragma unroll
      for (int j = 0; j < 4; ++j) {
        const int row = sr + 16 * j;
        *(ushort4*)&Xbf[row][skq * 4] =
            make_ushort4(f2bf(xp[j].x), f2bf(xp[j].y), f2bf(xp[j].z), f2bf(xp[j].w));
        *(ushort4*)&Wbf[row][skq * 4] =
            make_ushort4(f2bf(wp[j].x), f2bf(wp[j].y), f2bf(wp[j].z), f2bf(wp[j].w));
        if (do_reg) {
          float dx = wp[j].x - w0p[j].x, dy = wp[j].y - w0p[j].y;
          float dz = wp[j].z - w0p[j].z, dw = wp[j].w - w0p[j].w;
          regp += dx * dx + dy * dy + dz * dz + dw * dw;
        }
      }
      __syncthreads();  // LDS tile visible to all waves
      // ---- issue next chunk's global loads (land during compute) ----
      if (kc + BK < F_SZ) {
        const int ko = kc + BK;
#pragma unroll
        for (int j = 0; j < 4; ++j) {
          xp[j] = *(const float4*)(xptr[j] + ko);
          wp[j] = *(const float4*)(wptr[j] + ko);
        }
        if (do_reg)
#pragma unroll
          for (int j = 0; j < 4; ++j)
            w0p[j] = *(const float4*)(w0_mu + (size_t)(n0 + sr + 16 * j) * F_SZ + ko + skq * 4);
      }
      // ---- compute: 2 K-steps x 4 n-tiles of 16x16x32 bf16 MFMA ----
#pragma unroll
      for (int ks = 0; ks < 2; ++ks) {
        const bf16x8 a = *(const bf16x8*)(aF + ks * 32);
#pragma unroll
        for (int t = 0; t < 4; ++t) {
          const bf16x8 b = *(const bf16x8*)(bF + t * 16 * WSTR + ks * 32);
          acc[t] = __builtin_amdgcn_mfma_f32_16x16x32_bf16(a, b, acc[t], 0, 0, 0);
        }
      }
    }

    // ---- epilogue: bias + scatter. D layout: col=lane&15, row=quad*4+reg ----
    int orow[4];
#pragma unroll
    for (int i = 0; i < 4; ++i) {
      const int r = r0 + wave * 16 + fq * 4 + i;
      orow[i] = (r < cnt) ? wsi[WS_ORDER + rs + r] : -1;
    }
#pragma unroll
    for (int t = 0; t < 4; ++t) {
      const int gcol = n0 + 16 * t + fl;
      const float bias = b_mu[(g << 9) + gcol];
#pragma unroll
      for (int i = 0; i < 4; ++i)
        if (orow[i] >= 0) out[(size_t)orow[i] * U_SZ + gcol] = acc[t][i] + bias;
    }

    // ---- block-reduce reg partials, weight by cnt, one atomic ----
    if (do_reg) {
#pragma unroll
      for (int off = 32; off > 0; off >>= 1) regp += __shfl_down(regp, off);
      if (lane == 0) redw[wave] = regp;
      __syncthreads();
      if (tid == 0)
        atomicAdd((float*)&wsi[WS_WSF],
                  (float)cnt * (redw[0] + redw[1] + redw[2] + redw[3]));
    }
  }

  // ---- ticket: last block writes the scalar reg loss ----
  __threadfence();
  if (tid == 0) {
    const int total_blocks = gridDim.x * gridDim.y;
    if (atomicAdd(&wsi[WS_TICKET], 1) == total_blocks - 1) {
      float v = atomicAdd((float*)&wsi[WS_WSF], 0.0f);  // coherent read
      out[(size_t)B_SZ * U_SZ] = REG_STRENGTH * v;
    }
  }
}

extern "C" void kernel_launch(void* const* d_in, const int* in_sizes, int n_in,
                              void* d_out, int out_size, void* d_ws, size_t ws_size,
                              hipStream_t stream) {
  const float* x     = (const float*)d_in[0];
  const int*   gid   = (const int*)d_in[1];
  const float* w_mu  = (const float*)d_in[2];
  const float* b_mu  = (const float*)d_in[3];
  const float* w0_mu = (const float*)d_in[4];
  const float* b0_mu = (const float*)d_in[5];
  float* out = (float*)d_out;
  int* wsi = (int*)d_ws;

  prep_kernel<<<1, 1024, 0, stream>>>(gid, wsi);
  gemm_kernel<<<dim3(NTILES, MAXCHUNKS), 256, 0, stream>>>(
      x, w_mu, b_mu, w0_mu, b0_mu, out, wsi);
}